// Round 1
// baseline (50.881 us; speedup 1.0000x reference)
//
#include <hip/hip_runtime.h>
#include <math.h>

// MultiChannelXi: xi[b,t,k,:] = sum_{s<=t} alpha_k^(t-s) h[b,s,:] / Z_{k,t}
// with alpha = clip(sigmoid(raw_alpha), 1e-6, 1-1e-6),
// Z_{k,t} = sum_{j=0..t} alpha_k^j = (1 - alpha^(t+1)) / (1 - alpha).
// Implemented as a chunked parallel scan (3 kernels), fully memory-bound.

namespace {

constexpr int T_LEN  = 4096;
constexpr int D_DIM  = 512;
constexpr int D4     = D_DIM / 4;      // 128 float4 lanes per row
constexpr int K_CH   = 4;
constexpr int CHUNK  = 32;             // chunk length along T
constexpr int NCHUNK = T_LEN / CHUNK;  // 128 chunks

__device__ __forceinline__ float sigmoid_clip(float x) {
    float a = 1.0f / (1.0f + expf(-x));
    return fminf(fmaxf(a, 1e-6f), 1.0f - 1e-6f);
}

// Kernel 1: per-chunk weighted sums.
// L[b,c,k,:] = sum_{j=0..C-1} alpha_k^(C-1-j) * h[b, c*C+j, :]
__global__ void ema_chunk_sums(const float4* __restrict__ h4,
                               const float*  __restrict__ raw_alpha,
                               float4* __restrict__ lbuf) {
    const int c  = blockIdx.x % NCHUNK;
    const int b  = blockIdx.x / NCHUNK;
    const int d4 = threadIdx.x;

    float al[K_CH];
#pragma unroll
    for (int k = 0; k < K_CH; ++k) al[k] = sigmoid_clip(raw_alpha[k]);

    float4 acc[K_CH];
#pragma unroll
    for (int k = 0; k < K_CH; ++k) acc[k] = make_float4(0.f, 0.f, 0.f, 0.f);

    const float4* hp = h4 + ((size_t)b * T_LEN + (size_t)c * CHUNK) * D4 + d4;
    for (int j = 0; j < CHUNK; ++j) {
        float4 hv = hp[(size_t)j * D4];
#pragma unroll
        for (int k = 0; k < K_CH; ++k) {
            acc[k].x = fmaf(al[k], acc[k].x, hv.x);
            acc[k].y = fmaf(al[k], acc[k].y, hv.y);
            acc[k].z = fmaf(al[k], acc[k].z, hv.z);
            acc[k].w = fmaf(al[k], acc[k].w, hv.w);
        }
    }
#pragma unroll
    for (int k = 0; k < K_CH; ++k) {
        lbuf[(((size_t)b * NCHUNK + c) * K_CH + k) * D4 + d4] = acc[k];
    }
}

// Kernel 2: in-place exclusive scan across chunks.
// After: buf[b,c,k,:] = S[b, c*C - 1, k, :]  (state entering chunk c; 0 for c=0)
__global__ void ema_chunk_scan(const float* __restrict__ raw_alpha,
                               float4* __restrict__ buf, int total) {
    const int idx = blockIdx.x * blockDim.x + threadIdx.x;
    if (idx >= total) return;
    const int d4 = idx % D4;
    const int k  = (idx / D4) % K_CH;
    const int b  = idx / (D4 * K_CH);

    const float a  = sigmoid_clip(raw_alpha[k]);
    const float aC = exp2f((float)CHUNK * log2f(a));  // alpha^CHUNK

    float4 pre = make_float4(0.f, 0.f, 0.f, 0.f);
    for (int c = 0; c < NCHUNK; ++c) {
        const size_t off = (((size_t)b * NCHUNK + c) * K_CH + k) * D4 + d4;
        const float4 L = buf[off];
        buf[off] = pre;
        pre.x = fmaf(aC, pre.x, L.x);
        pre.y = fmaf(aC, pre.y, L.y);
        pre.z = fmaf(aC, pre.z, L.z);
        pre.w = fmaf(aC, pre.w, L.w);
    }
}

// Kernel 3: re-scan within chunk starting from the chunk prefix, normalize, write.
__global__ void ema_apply(const float4* __restrict__ h4,
                          const float*  __restrict__ raw_alpha,
                          const float4* __restrict__ pbuf,
                          float4* __restrict__ out4) {
    const int c  = blockIdx.x % NCHUNK;
    const int b  = blockIdx.x / NCHUNK;
    const int d4 = threadIdx.x;
    const int t0 = c * CHUNK;

    float al[K_CH], om[K_CH], pw[K_CH];
#pragma unroll
    for (int k = 0; k < K_CH; ++k) {
        const float a = sigmoid_clip(raw_alpha[k]);
        al[k] = a;
        om[k] = 1.0f - a;
        pw[k] = exp2f((float)(t0 + 1) * log2f(a));  // alpha^(t0+1) = alpha^(t+1) at j=0
    }

    float4 S[K_CH];
#pragma unroll
    for (int k = 0; k < K_CH; ++k)
        S[k] = pbuf[(((size_t)b * NCHUNK + c) * K_CH + k) * D4 + d4];

    const float4* hp = h4 + ((size_t)b * T_LEN + t0) * D4 + d4;
    float4* op = out4 + (((size_t)b * T_LEN + t0) * (size_t)K_CH) * D4 + d4;

    for (int j = 0; j < CHUNK; ++j) {
        const float4 hv = hp[(size_t)j * D4];
#pragma unroll
        for (int k = 0; k < K_CH; ++k) {
            S[k].x = fmaf(al[k], S[k].x, hv.x);
            S[k].y = fmaf(al[k], S[k].y, hv.y);
            S[k].z = fmaf(al[k], S[k].z, hv.z);
            S[k].w = fmaf(al[k], S[k].w, hv.w);
            const float invZ = om[k] / fmaxf(1.0f - pw[k], 1e-30f);
            float4 o;
            o.x = S[k].x * invZ;
            o.y = S[k].y * invZ;
            o.z = S[k].z * invZ;
            o.w = S[k].w * invZ;
            op[((size_t)j * K_CH + k) * D4] = o;
            pw[k] *= al[k];
        }
    }
}

} // namespace

extern "C" void kernel_launch(void* const* d_in, const int* in_sizes, int n_in,
                              void* d_out, int out_size, void* d_ws, size_t ws_size,
                              hipStream_t stream) {
    const float* h         = (const float*)d_in[0];
    const float* raw_alpha = (const float*)d_in[1];
    float* out = (float*)d_out;

    const int B = in_sizes[0] / (T_LEN * D_DIM);  // 4

    float4* lbuf = (float4*)d_ws;  // B*NCHUNK*K_CH*D_DIM floats = 4 MB

    const dim3 blk(D4);            // 128 threads = 2 waves
    const dim3 grid1(B * NCHUNK);  // 512 blocks

    hipLaunchKernelGGL(ema_chunk_sums, grid1, blk, 0, stream,
                       (const float4*)h, raw_alpha, lbuf);

    const int total = B * K_CH * D4;  // 2048
    hipLaunchKernelGGL(ema_chunk_scan, dim3((total + 255) / 256), dim3(256), 0, stream,
                       raw_alpha, lbuf, total);

    hipLaunchKernelGGL(ema_apply, grid1, blk, 0, stream,
                       (const float4*)h, raw_alpha, (const float4*)lbuf, (float4*)out);
}